// Round 4
// baseline (342.569 us; speedup 1.0000x reference)
//
#include <hip/hip_runtime.h>
#include <hip/hip_bf16.h>
#include <stdint.h>

// Problem constants
#define Bq 1024
#define Dq 512
#define Nq 16
#define Hq 512
#define Mq (Bq*Nq)   // 16384

typedef short v8s  __attribute__((ext_vector_type(8)));
typedef float v16f __attribute__((ext_vector_type(16)));
typedef int   v4i  __attribute__((ext_vector_type(4)));

typedef __attribute__((address_space(3))) unsigned int as3_u32;
typedef __attribute__((address_space(1))) const unsigned int as1_u32;

__device__ __forceinline__ unsigned short f2bf(float f) {
  union { float f; unsigned u; } v; v.f = f;
  return (unsigned short)((v.u + 0x7fffu + ((v.u >> 16) & 1u)) >> 16);
}

// Xb[b*16+n][d] = bf16(x[b][d][n])
__global__ void k_transpose_x(const float* __restrict__ x, unsigned short* __restrict__ xb) {
  __shared__ float lds[Dq][Nq + 1];
  const int b = blockIdx.x;
  const float* xi = x + (size_t)b * Dq * Nq;
  const int t = threadIdx.x;
  for (int p = 0; p < (Dq*Nq)/256; ++p) {
    int i = t + p*256;
    lds[i >> 4][i & (Nq-1)] = xi[i];
  }
  __syncthreads();
  unsigned short* o = xb + (size_t)b * Nq * Dq;
  for (int p = 0; p < (Dq*Nq)/256; ++p) {
    int i = t + p*256;
    o[i] = f2bf(lds[i & (Dq-1)][i >> 9]);   // i = n*512 + d
  }
}

// One dispatch for all weight transposes: z=0 -> Ws1, z=1 -> Ws2, z>=2 -> Wc1[z-2]
// out[z][c][r] = bf16(in[z][r][c]), 512x512 each
__global__ void k_transpose_w(const float* __restrict__ Ws1, const float* __restrict__ Ws2,
                              const float* __restrict__ Wc1,
                              unsigned short* __restrict__ Ws1t, unsigned short* __restrict__ Ws2t,
                              unsigned short* __restrict__ Wc1t) {
  __shared__ float tile[32][33];
  const int z = blockIdx.z;
  const float* in;
  unsigned short* out;
  if (z == 0)      { in = Ws1; out = Ws1t; }
  else if (z == 1) { in = Ws2; out = Ws2t; }
  else             { in = Wc1 + (size_t)(z-2) * 512 * 512; out = Wc1t + (size_t)(z-2) * 512 * 512; }
  const int tx = threadIdx.x, ty = threadIdx.y;  // (32,8)
  const int c0 = blockIdx.x * 32, r0 = blockIdx.y * 32;
#pragma unroll
  for (int j = 0; j < 4; ++j)
    tile[ty + j*8][tx] = in[(size_t)(r0 + ty + j*8) * 512 + c0 + tx];
  __syncthreads();
#pragma unroll
  for (int j = 0; j < 4; ++j) {
    int c = c0 + ty + j*8;   // output row (input col)
    int r = r0 + tx;         // output col (input row)
    out[(size_t)c * 512 + r] = f2bf(tile[tx][ty + j*8]);
  }
}

// BMx128 tile MFMA GEMM (v_mfma_f32_32x32x16_bf16), K=512, Nout=512.
// A: MxK bf16 row-major, Bt: Nout x K bf16 (per z).
// Staging via global_load_lds width=16; XOR-swizzled 16B chunks: chunk c of row r
// stored at slot c ^ ((r>>1)&3) -> fragment ds_read_b128 is 2-way bank aliased (free).
// Fragment chunk for k-half kh: c = kh*2 + (lane>>5)  [lane's 8 elems cover
// k = kh*16 + (lane>>5)*8 + j  — the R3 bug read c = kh].
// BM=128 (MODE 0): 4 waves in 2x2, wave tile 64x64 (2x2 MFMA).
// BM=256 (MODE 1): 4 waves stacked in M, wave tile 64x128 (2x4 MFMA) — 16 MFMA/barrier.
// MODE 0: out = lrelu(A@B + bias) as bf16 (row permuted to m=(r&15)*1024+(r>>4) if permute).
// MODE 1: per-head (z): atomicAdd into FL[m][z] of sum_h lrelu(A@B + bc1[z])*Wc2[z][h].
template<int MODE, int BM>
__global__ __launch_bounds__(256, 2)
void k_gemm(const unsigned short* __restrict__ A,
            const unsigned short* __restrict__ Bt,
            const float* __restrict__ bias,
            void* __restrict__ out_,
            const float* __restrict__ w2,
            int permute) {
  constexpr int BN = 128, BK = 32, KD = 512;
  constexpr int NI = (BM == 256) ? 4 : 2;
  constexpr int AG = BM / 16;          // 16-row staging groups for A
  __shared__ __align__(16) unsigned short As[BM][BK];
  __shared__ __align__(16) unsigned short Bs[BN][BK];

  const int t = threadIdx.x;
  const int wave = t >> 6, lane = t & 63;
  const int wr = (BM == 256) ? wave : (wave >> 1);
  const int wc = (BM == 256) ? 0    : (wave & 1);
  const int l32 = lane & 31, kh0 = lane >> 5;
  const int bm = blockIdx.x * BM, bn = blockIdx.y * BN;
  const int z = blockIdx.z;

  const unsigned short* Bz = Bt + (size_t)z * KD * 512;
  const float* biasz = bias + (size_t)z * 512;

  const int lrow = lane >> 2;          // 0..15 within a 16-row staging group
  const int lslot = lane & 3;

  v16f acc[2][NI] = {};

  for (int kt = 0; kt < KD / BK; ++kt) {
#pragma unroll
    for (int i = wave; i < AG + 8; i += 4) {
      const int isA = (i < AG);
      const int r0 = (isA ? i : i - AG) * 16;
      const int row = r0 + lrow;
      const int cg = lslot ^ ((row >> 1) & 3);       // swizzled global chunk
      const unsigned short* g = isA ? &A [(size_t)(bm + row) * KD + kt*BK + cg*8]
                                    : &Bz[(size_t)(bn + row) * KD + kt*BK + cg*8];
      as3_u32* d = isA ? (as3_u32*)&As[r0][0] : (as3_u32*)&Bs[r0][0];
      __builtin_amdgcn_global_load_lds((as1_u32*)g, d, 16, 0, 0);
    }
    __syncthreads();
    v8s af[2][2], bf[NI][2];
#pragma unroll
    for (int mi = 0; mi < 2; ++mi) {
      int ra = wr*64 + mi*32 + l32;
#pragma unroll
      for (int kh = 0; kh < 2; ++kh) {
        int c = kh*2 + kh0;                          // correct global chunk for this k-half
        af[mi][kh] = *(const v8s*)&As[ra][(c ^ ((ra >> 1) & 3)) * 8];
      }
    }
#pragma unroll
    for (int ni = 0; ni < NI; ++ni) {
      int rb = wc*64 + ni*32 + l32;
#pragma unroll
      for (int kh = 0; kh < 2; ++kh) {
        int c = kh*2 + kh0;
        bf[ni][kh] = *(const v8s*)&Bs[rb][(c ^ ((rb >> 1) & 3)) * 8];
      }
    }
#pragma unroll
    for (int kh = 0; kh < 2; ++kh)
#pragma unroll
      for (int mi = 0; mi < 2; ++mi)
#pragma unroll
        for (int ni = 0; ni < NI; ++ni)
          acc[mi][ni] = __builtin_amdgcn_mfma_f32_32x32x16_bf16(af[mi][kh], bf[ni][kh], acc[mi][ni], 0, 0, 0);
    __syncthreads();
  }

  if (MODE == 0) {
    unsigned short* O = (unsigned short*)out_;
#pragma unroll
    for (int mi = 0; mi < 2; ++mi) {
#pragma unroll
      for (int ni = 0; ni < NI; ++ni) {
        int col = bn + wc*64 + ni*32 + l32;
        float bcol = biasz[col];
#pragma unroll
        for (int reg = 0; reg < 16; ++reg) {
          int rl = (reg & 3) + 8*(reg >> 2) + 4*kh0;
          int grow = bm + wr*64 + mi*32 + rl;
          int orow = permute ? ((grow & 15) * Bq + (grow >> 4)) : grow;
          float v = acc[mi][ni][reg] + bcol;
          v = v >= 0.f ? v : 0.1f * v;
          O[(size_t)orow * 512 + col] = f2bf(v);
        }
      }
    }
  } else {
    float* FL = (float*)out_;             // [Mq][Nq]
    const float* w2z = w2 + (size_t)z * 512;
#pragma unroll
    for (int mi = 0; mi < 2; ++mi) {
#pragma unroll
      for (int reg = 0; reg < 16; ++reg) {
        int rl = (reg & 3) + 8*(reg >> 2) + 4*kh0;
        float s = 0.f;
#pragma unroll
        for (int ni = 0; ni < NI; ++ni) {
          int col = bn + ni*32 + l32;
          float v = acc[mi][ni][reg] + biasz[col];
          v = v >= 0.f ? v : 0.1f * v;
          s += v * w2z[col];
        }
        // reduce 32 columns within each 32-lane half (row differs across halves)
#pragma unroll
        for (int off = 1; off < 32; off <<= 1)
          s += __shfl_xor(s, off, 64);
        if (l32 == 0) {
          int grow = bm + wave*64 + mi*32 + rl;
          atomicAdd(&FL[(size_t)grow * Nq + z], s);
        }
      }
    }
  }
}

// full_out[m][n] = FL[m][n] + bc2[n]; out[b][n] = sigmoid(full_out[n*B+b][n])
__global__ void k_final(const float* __restrict__ fl, const float* __restrict__ bc2,
                        float* __restrict__ out) {
  int i = blockIdx.x * 256 + threadIdx.x;   // i over Mq*Nq
  int m = i >> 4, n = i & 15;
  float v = fl[i] + bc2[n];
  out[Mq + i] = v;                           // full_out, offset by |out| = 16384
  if (n == (m >> 10)) {                      // diagonal: m = n*B + b
    int b = m & (Bq - 1);
    out[b * Nq + n] = 1.f / (1.f + __expf(-v));
  }
}

extern "C" void kernel_launch(void* const* d_in, const int* in_sizes, int n_in,
                              void* d_out, int out_size, void* d_ws, size_t ws_size,
                              hipStream_t stream) {
  (void)in_sizes; (void)n_in; (void)out_size; (void)ws_size;
  const float* x   = (const float*)d_in[0];
  const float* Ws1 = (const float*)d_in[1];
  const float* bs1 = (const float*)d_in[2];
  const float* Ws2 = (const float*)d_in[3];
  const float* bs2 = (const float*)d_in[4];
  const float* Wc1 = (const float*)d_in[5];
  const float* bc1 = (const float*)d_in[6];
  const float* Wc2 = (const float*)d_in[7];
  const float* bc2 = (const float*)d_in[8];

  char* ws = (char*)d_ws;
  unsigned short* Xb   = (unsigned short*)(ws);                          // 16 MB
  unsigned short* Hbuf = (unsigned short*)(ws + (size_t)16*1024*1024);   // 16 MB
  unsigned short* Sm   = (unsigned short*)(ws + (size_t)32*1024*1024);   // 16 MB
  unsigned short* Ws1t = (unsigned short*)(ws + (size_t)48*1024*1024);   // 512 KB
  unsigned short* Ws2t = (unsigned short*)(ws + (size_t)48*1024*1024 + 512*1024);
  unsigned short* Wc1t = (unsigned short*)(ws + (size_t)49*1024*1024);   // 8 MB
  float*          FL   = (float*)         (ws + (size_t)57*1024*1024);   // 1 MB

  hipMemsetAsync(FL, 0, (size_t)Mq * Nq * sizeof(float), stream);

  k_transpose_x<<<Bq, 256, 0, stream>>>(x, Xb);
  k_transpose_w<<<dim3(16,16,18), dim3(32,8), 0, stream>>>(Ws1, Ws2, Wc1, Ws1t, Ws2t, Wc1t);

  // shared MLP: H = lrelu(Xb@Ws1+bs1); Sm = lrelu(H@Ws2+bs2) in m = n*B+b row order
  k_gemm<0,128><<<dim3(128,4,1), 256, 0, stream>>>(Xb,   Ws1t, bs1, Hbuf, nullptr, 0);
  k_gemm<0,128><<<dim3(128,4,1), 256, 0, stream>>>(Hbuf, Ws2t, bs2, Sm,   nullptr, 1);
  // fused per-head GEMM + H-reduction into FL (BM=256: 16 MFMA per barrier)
  k_gemm<1,256><<<dim3(64,4,16), 256, 0, stream>>>(Sm, Wc1t, bc1, FL, Wc2, 0);

  k_final<<<(Mq*Nq)/256, 256, 0, stream>>>(FL, bc2, (float*)d_out);
}

// Round 5
// 326.571 us; speedup vs baseline: 1.0490x; 1.0490x over previous
//
#include <hip/hip_runtime.h>
#include <hip/hip_bf16.h>
#include <stdint.h>

// Problem constants
#define Bq 1024
#define Dq 512
#define Nq 16
#define Hq 512
#define Mq (Bq*Nq)   // 16384

typedef short v8s  __attribute__((ext_vector_type(8)));
typedef float v16f __attribute__((ext_vector_type(16)));

typedef __attribute__((address_space(3))) unsigned int as3_u32;
typedef __attribute__((address_space(1))) const unsigned int as1_u32;

__device__ __forceinline__ unsigned short f2bf(float f) {
  union { float f; unsigned u; } v; v.f = f;
  return (unsigned short)((v.u + 0x7fffu + ((v.u >> 16) & 1u)) >> 16);
}

// Xb[b*16+n][d] = bf16(x[b][d][n])
__global__ void k_transpose_x(const float* __restrict__ x, unsigned short* __restrict__ xb) {
  __shared__ float lds[Dq][Nq + 1];
  const int b = blockIdx.x;
  const float* xi = x + (size_t)b * Dq * Nq;
  const int t = threadIdx.x;
  for (int p = 0; p < (Dq*Nq)/256; ++p) {
    int i = t + p*256;
    lds[i >> 4][i & (Nq-1)] = xi[i];
  }
  __syncthreads();
  unsigned short* o = xb + (size_t)b * Nq * Dq;
  for (int p = 0; p < (Dq*Nq)/256; ++p) {
    int i = t + p*256;
    o[i] = f2bf(lds[i & (Dq-1)][i >> 9]);   // i = n*512 + d
  }
}

// One dispatch for all weight transposes: z=0 -> Ws1, z=1 -> Ws2, z>=2 -> Wc1[z-2]
// out[z][c][r] = bf16(in[z][r][c]), 512x512 each
__global__ void k_transpose_w(const float* __restrict__ Ws1, const float* __restrict__ Ws2,
                              const float* __restrict__ Wc1,
                              unsigned short* __restrict__ Ws1t, unsigned short* __restrict__ Ws2t,
                              unsigned short* __restrict__ Wc1t) {
  __shared__ float tile[32][33];
  const int z = blockIdx.z;
  const float* in;
  unsigned short* out;
  if (z == 0)      { in = Ws1; out = Ws1t; }
  else if (z == 1) { in = Ws2; out = Ws2t; }
  else             { in = Wc1 + (size_t)(z-2) * 512 * 512; out = Wc1t + (size_t)(z-2) * 512 * 512; }
  const int tx = threadIdx.x, ty = threadIdx.y;  // (32,8)
  const int c0 = blockIdx.x * 32, r0 = blockIdx.y * 32;
#pragma unroll
  for (int j = 0; j < 4; ++j)
    tile[ty + j*8][tx] = in[(size_t)(r0 + ty + j*8) * 512 + c0 + tx];
  __syncthreads();
#pragma unroll
  for (int j = 0; j < 4; ++j) {
    int c = c0 + ty + j*8;   // output row (input col)
    int r = r0 + tx;         // output col (input row)
    out[(size_t)c * 512 + r] = f2bf(tile[tx][ty + j*8]);
  }
}

// BMx128 tile MFMA GEMM (v_mfma_f32_32x32x16_bf16), K=512, Nout=512.
// Double-buffered LDS: global_load_lds(kt+1) issued BEFORE kt's ds_reads/MFMA so the
// barrier's vmcnt(0) drain targets loads already ~300 cycles in flight (the R4 loop
// drained them immediately after issue — full latency exposed every kt).
// XOR-swizzled 16B chunks: chunk c of row r stored at slot c ^ ((r>>1)&3).
// Fragment chunk for k-half kh: c = kh*2 + (lane>>5).
// MODE 0: out = lrelu(A@B + bias) as bf16 (row permuted to m=(r&15)*1024+(r>>4) if permute).
// MODE 1: per-head (z): atomicAdd into FL[m][z] of sum_h lrelu(A@B + bc1[z])*Wc2[z][h].
template<int MODE, int BM>
__global__ __launch_bounds__(256, 2)
void k_gemm(const unsigned short* __restrict__ A,
            const unsigned short* __restrict__ Bt,
            const float* __restrict__ bias,
            void* __restrict__ out_,
            const float* __restrict__ w2,
            int permute) {
  constexpr int BN = 128, BK = 32, KD = 512;
  constexpr int NI = (BM == 256) ? 4 : 2;
  constexpr int AG = BM / 16;          // 16-row staging groups for A
  constexpr int TG = AG + BN / 16;     // total groups per buffer
  __shared__ __align__(16) unsigned short As[2][BM][BK];
  __shared__ __align__(16) unsigned short Bs[2][BN][BK];

  const int t = threadIdx.x;
  const int wave = t >> 6, lane = t & 63;
  const int wr = (BM == 256) ? wave : (wave >> 1);
  const int wc = (BM == 256) ? 0    : (wave & 1);
  const int l32 = lane & 31, kh0 = lane >> 5;
  const int bm = blockIdx.x * BM, bn = blockIdx.y * BN;
  const int z = blockIdx.z;

  const unsigned short* Bz = Bt + (size_t)z * KD * 512;
  const float* biasz = bias + (size_t)z * 512;

  const int lrow = lane >> 2;          // 0..15 within a 16-row staging group
  const int lslot = lane & 3;

  auto stage = [&](int buf, int kt) {
#pragma unroll
    for (int i = wave; i < TG; i += 4) {
      const int isA = (i < AG);
      const int r0 = (isA ? i : i - AG) * 16;
      const int row = r0 + lrow;
      const int cg = lslot ^ ((row >> 1) & 3);       // swizzled global chunk
      const unsigned short* g = isA ? &A [(size_t)(bm + row) * KD + kt*BK + cg*8]
                                    : &Bz[(size_t)(bn + row) * KD + kt*BK + cg*8];
      as3_u32* d = isA ? (as3_u32*)&As[buf][r0][0] : (as3_u32*)&Bs[buf][r0][0];
      __builtin_amdgcn_global_load_lds((as1_u32*)g, d, 16, 0, 0);
    }
  };

  v16f acc[2][NI] = {};

  stage(0, 0);
  __syncthreads();

  for (int kt = 0; kt < KD / BK; ++kt) {
    const int cur = kt & 1;
    if (kt + 1 < KD / BK) stage(cur ^ 1, kt + 1);

    v8s af[2][2], bf[NI][2];
#pragma unroll
    for (int mi = 0; mi < 2; ++mi) {
      int ra = wr*64 + mi*32 + l32;
#pragma unroll
      for (int kh = 0; kh < 2; ++kh) {
        int c = kh*2 + kh0;                          // global chunk for this k-half
        af[mi][kh] = *(const v8s*)&As[cur][ra][(c ^ ((ra >> 1) & 3)) * 8];
      }
    }
#pragma unroll
    for (int ni = 0; ni < NI; ++ni) {
      int rb = wc*64 + ni*32 + l32;
#pragma unroll
      for (int kh = 0; kh < 2; ++kh) {
        int c = kh*2 + kh0;
        bf[ni][kh] = *(const v8s*)&Bs[cur][rb][(c ^ ((rb >> 1) & 3)) * 8];
      }
    }
#pragma unroll
    for (int kh = 0; kh < 2; ++kh)
#pragma unroll
      for (int mi = 0; mi < 2; ++mi)
#pragma unroll
        for (int ni = 0; ni < NI; ++ni)
          acc[mi][ni] = __builtin_amdgcn_mfma_f32_32x32x16_bf16(af[mi][kh], bf[ni][kh], acc[mi][ni], 0, 0, 0);
    __syncthreads();
  }

  if (MODE == 0) {
    unsigned short* O = (unsigned short*)out_;
#pragma unroll
    for (int mi = 0; mi < 2; ++mi) {
#pragma unroll
      for (int ni = 0; ni < NI; ++ni) {
        int col = bn + wc*64 + ni*32 + l32;
        float bcol = biasz[col];
#pragma unroll
        for (int reg = 0; reg < 16; ++reg) {
          int rl = (reg & 3) + 8*(reg >> 2) + 4*kh0;
          int grow = bm + wr*64 + mi*32 + rl;
          int orow = permute ? ((grow & 15) * Bq + (grow >> 4)) : grow;
          float v = acc[mi][ni][reg] + bcol;
          v = v >= 0.f ? v : 0.1f * v;
          O[(size_t)orow * 512 + col] = f2bf(v);
        }
      }
    }
  } else {
    float* FL = (float*)out_;             // [Mq][Nq]
    const float* w2z = w2 + (size_t)z * 512;
#pragma unroll
    for (int mi = 0; mi < 2; ++mi) {
#pragma unroll
      for (int reg = 0; reg < 16; ++reg) {
        int rl = (reg & 3) + 8*(reg >> 2) + 4*kh0;
        float s = 0.f;
#pragma unroll
        for (int ni = 0; ni < NI; ++ni) {
          int col = bn + ni*32 + l32;
          float v = acc[mi][ni][reg] + biasz[col];
          v = v >= 0.f ? v : 0.1f * v;
          s += v * w2z[col];
        }
        // reduce 32 columns within each 32-lane half (row differs across halves)
#pragma unroll
        for (int off = 1; off < 32; off <<= 1)
          s += __shfl_xor(s, off, 64);
        if (l32 == 0) {
          int grow = bm + wave*64 + mi*32 + rl;
          atomicAdd(&FL[(size_t)grow * Nq + z], s);
        }
      }
    }
  }
}

// full_out[m][n] = FL[m][n] + bc2[n]; out[b][n] = sigmoid(full_out[n*B+b][n])
__global__ void k_final(const float* __restrict__ fl, const float* __restrict__ bc2,
                        float* __restrict__ out) {
  int i = blockIdx.x * 256 + threadIdx.x;   // i over Mq*Nq
  int m = i >> 4, n = i & 15;
  float v = fl[i] + bc2[n];
  out[Mq + i] = v;                           // full_out, offset by |out| = 16384
  if (n == (m >> 10)) {                      // diagonal: m = n*B + b
    int b = m & (Bq - 1);
    out[b * Nq + n] = 1.f / (1.f + __expf(-v));
  }
}

extern "C" void kernel_launch(void* const* d_in, const int* in_sizes, int n_in,
                              void* d_out, int out_size, void* d_ws, size_t ws_size,
                              hipStream_t stream) {
  (void)in_sizes; (void)n_in; (void)out_size; (void)ws_size;
  const float* x   = (const float*)d_in[0];
  const float* Ws1 = (const float*)d_in[1];
  const float* bs1 = (const float*)d_in[2];
  const float* Ws2 = (const float*)d_in[3];
  const float* bs2 = (const float*)d_in[4];
  const float* Wc1 = (const float*)d_in[5];
  const float* bc1 = (const float*)d_in[6];
  const float* Wc2 = (const float*)d_in[7];
  const float* bc2 = (const float*)d_in[8];

  char* ws = (char*)d_ws;
  unsigned short* Xb   = (unsigned short*)(ws);                          // 16 MB
  unsigned short* Hbuf = (unsigned short*)(ws + (size_t)16*1024*1024);   // 16 MB
  unsigned short* Sm   = (unsigned short*)(ws + (size_t)32*1024*1024);   // 16 MB
  unsigned short* Ws1t = (unsigned short*)(ws + (size_t)48*1024*1024);   // 512 KB
  unsigned short* Ws2t = (unsigned short*)(ws + (size_t)48*1024*1024 + 512*1024);
  unsigned short* Wc1t = (unsigned short*)(ws + (size_t)49*1024*1024);   // 8 MB
  float*          FL   = (float*)         (ws + (size_t)57*1024*1024);   // 1 MB

  hipMemsetAsync(FL, 0, (size_t)Mq * Nq * sizeof(float), stream);

  k_transpose_x<<<Bq, 256, 0, stream>>>(x, Xb);
  k_transpose_w<<<dim3(16,16,18), dim3(32,8), 0, stream>>>(Ws1, Ws2, Wc1, Ws1t, Ws2t, Wc1t);

  // shared MLP: H = lrelu(Xb@Ws1+bs1); Sm = lrelu(H@Ws2+bs2) in m = n*B+b row order
  k_gemm<0,128><<<dim3(128,4,1), 256, 0, stream>>>(Xb,   Ws1t, bs1, Hbuf, nullptr, 0);
  k_gemm<0,128><<<dim3(128,4,1), 256, 0, stream>>>(Hbuf, Ws2t, bs2, Sm,   nullptr, 1);
  // fused per-head GEMM + H-reduction into FL (BM=256, double-buffered)
  k_gemm<1,256><<<dim3(64,4,16), 256, 0, stream>>>(Sm, Wc1t, bc1, FL, Wc2, 0);

  k_final<<<(Mq*Nq)/256, 256, 0, stream>>>(FL, bc2, (float*)d_out);
}